// Round 3
// baseline (450.573 us; speedup 1.0000x reference)
//
#include <hip/hip_runtime.h>

// B=4,H=16,S=1024,D=64. Outputs: out [64,1024,64] fp32 then attn [64,1024,1024] fp32.
// Fused single loop (flat softmax, no online max -- scores bounded, exp can't overflow):
//   per kt: prefetch K/V(kt+1) -> QK^T(kt) -> e=exp(x*scale+bias) -> xs regs (f32) +
//           sP (bf16 raw e) -> PV(kt) on UNNORMALIZED e (linear; scale by linv at end).
//   Zero global stores inside the loop; attn written in a barrier-free NT burst epilogue.
// All LDS XOR-swizzled (no pads): kills the 16-way sP-write bank conflict.
constexpr int SEQ = 1024;
constexpr int DH  = 64;
constexpr int QR  = 32;        // q rows per block
constexpr int KT  = 128;       // key tile
constexpr int NKT = SEQ / KT;  // 8

// LDS layout (bytes):
constexpr int SK0 = 0;         // K buf0: [128 keys][64 d] bf16, 128 B/row, swz (row&7)<<4
constexpr int SK1 = 16384;     // K buf1
constexpr int SV0 = 32768;     // V^T buf0: [64 d][128 keys] bf16, 256 B/row, swz (row&15)<<4
constexpr int SV1 = 49152;     // V^T buf1
constexpr int SPO = 65536;     // P: [32 q][128 keys] bf16, 256 B/row, swz (row&15)<<4 (single buf)
constexpr int SQO = 73728;     // Q: [32 q][64 d] bf16, 128 B/row, swz (row&7)<<4
constexpr int SRL = 77824;     // float[2][32] row sums
constexpr int SMEM_BYTES = 78080;   // -> 2 blocks/CU (VGPR caps at 2 anyway)

typedef __bf16 bf16x8 __attribute__((ext_vector_type(8)));
typedef __bf16 bf16x4 __attribute__((ext_vector_type(4)));
typedef float  f32x4  __attribute__((ext_vector_type(4)));

__device__ __forceinline__ char* kadr(char* s, int base, int row, int colB) {
    return s + base + row * 128 + (colB ^ ((row & 7) << 4));
}
__device__ __forceinline__ char* vadr(char* s, int base, int row, int colB) {
    return s + base + row * 256 + (colB ^ ((row & 15) << 4));
}

__global__ __launch_bounds__(256, 2)
void attn_flash_kernel(const float* __restrict__ Q, const float* __restrict__ K,
                       const float* __restrict__ V, const float* __restrict__ bias,
                       float* __restrict__ out, float* __restrict__ attn)
{
    __shared__ __align__(16) char smem[SMEM_BYTES];

    const int tid = threadIdx.x;
    const int l   = tid & 63;
    const int w   = tid >> 6;
    const int qt  = w & 1;             // q subtile (16 rows)
    const int ch  = w >> 1;            // column half (64 keys of the 128 tile)
    const int lm  = l & 15;
    const int lq  = l >> 4;
    const int j4  = lm & 3;            // transpose lane sub-index
    const int m0v = lm & 12;           // 4-col chunk base within 16
    // qb-major: head = blk & 63 -> head h pinned to XCD h%8; per-XCD K/V set = 4 MB = L2.
    const int head = blockIdx.x & 63;
    const int q0   = (blockIdx.x >> 6) * QR;
    const float scale = 0.125f;

    const float* Qh = Q + (size_t)head * SEQ * DH;
    const float* Kh = K + (size_t)head * SEQ * DH;
    const float* Vh = V + (size_t)head * SEQ * DH;
    float* outh  = out  + (size_t)head * SEQ * DH;
    float* attnh = attn + (size_t)head * SEQ * SEQ;

    const int srow = tid >> 4;         // K/Q staging row (16 rows per 256-thread step)
    const int sdg  = tid & 15;         // staging 4-float group
    const int vkb  = tid & 31;         // V staging: k group (4 keys)
    const int vdb0 = tid >> 5;         // V staging: d group base

    // ---- prologue: issue tile-0 K/V loads ----
    f32x4 kv[8], vv[2][4];
    #pragma unroll
    for (int i = 0; i < 8; ++i)
        kv[i] = *(const f32x4*)(Kh + (size_t)(srow + 16 * i) * DH + sdg * 4);
    #pragma unroll
    for (int i = 0; i < 2; ++i)
        #pragma unroll
        for (int jj = 0; jj < 4; ++jj)
            vv[i][jj] = *(const f32x4*)(Vh + (size_t)(vkb * 4 + jj) * DH + (vdb0 + 8 * i) * 4);

    // ---- stage Q (swizzled) ----
    #pragma unroll
    for (int i = 0; i < 2; ++i) {
        int row = srow + 16 * i;
        f32x4 v = *(const f32x4*)(Qh + (size_t)(q0 + row) * DH + sdg * 4);
        bf16x4 b;
        b[0] = (__bf16)v[0]; b[1] = (__bf16)v[1]; b[2] = (__bf16)v[2]; b[3] = (__bf16)v[3];
        *(bf16x4*)kadr(smem, SQO, row, sdg * 8) = b;
    }
    // ---- write tile-0 K/V to buf0 ----
    #pragma unroll
    for (int i = 0; i < 8; ++i) {
        bf16x4 b;
        b[0] = (__bf16)kv[i][0]; b[1] = (__bf16)kv[i][1];
        b[2] = (__bf16)kv[i][2]; b[3] = (__bf16)kv[i][3];
        *(bf16x4*)kadr(smem, SK0, srow + 16 * i, sdg * 8) = b;
    }
    #pragma unroll
    for (int i = 0; i < 2; ++i) {
        int d0 = (vdb0 + 8 * i) * 4;
        #pragma unroll
        for (int jj = 0; jj < 4; ++jj) {
            bf16x4 b;
            b[0] = (__bf16)vv[i][0][jj]; b[1] = (__bf16)vv[i][1][jj];
            b[2] = (__bf16)vv[i][2][jj]; b[3] = (__bf16)vv[i][3][jj];
            *(bf16x4*)vadr(smem, SV0, d0 + jj, vkb * 8) = b;
        }
    }
    __syncthreads();

    bf16x8 aQ0 = *(const bf16x8*)kadr(smem, SQO, qt * 16 + lm, lq * 16);
    bf16x8 aQ1 = *(const bf16x8*)kadr(smem, SQO, qt * 16 + lm, 64 + lq * 16);

    f32x4 xs[NKT][4];                  // 128 VGPR: e values (f32) for this thread
    float ssum[4] = {0.f, 0.f, 0.f, 0.f};
    f32x4 oacc[2] = {{0,0,0,0},{0,0,0,0}};
    const int dtb    = ch * 2;         // 2 d-subtiles of 16 per wave
    const int rowg_l = qt * 16 + lq * 4;   // tile-local first of 4 q rows (C-layout)

    // Schedule per kt (2 barriers): loads(kt+1) | QK(kt)+exp | B1 | LDS writes (kt+1, sP kt)
    // | B2 | PV(kt). B1 separates PV(kt-1) reads from the buffer/sP overwrites; B2 makes
    // sP(kt) + K/V(kt+1) visible. No barrier between PV(kt) and QK(kt+1) -> MFMA clusters.
    #pragma unroll
    for (int kt = 0; kt < NKT; ++kt) {
        const int curK = (kt & 1) ? SK1 : SK0;
        const int curV = (kt & 1) ? SV1 : SV0;
        const int nxtK = (kt & 1) ? SK0 : SK1;
        const int nxtV = (kt & 1) ? SV0 : SV1;

        // 1. issue next-tile K/V loads (in flight through QK+exp, consumed after B1)
        if (kt < NKT - 1) {
            #pragma unroll
            for (int i = 0; i < 8; ++i)
                kv[i] = *(const f32x4*)(Kh + (size_t)((kt + 1) * KT + srow + 16 * i) * DH + sdg * 4);
            #pragma unroll
            for (int i = 0; i < 2; ++i)
                #pragma unroll
                for (int jj = 0; jj < 4; ++jj)
                    vv[i][jj] = *(const f32x4*)(Vh + (size_t)((kt + 1) * KT + vkb * 4 + jj) * DH + (vdb0 + 8 * i) * 4);
        }
        // bias loads for this tile (hidden under QK MFMA)
        const int colg = kt * KT + ch * 64 + lm;
        float bb[4][4];
        #pragma unroll
        for (int r = 0; r < 4; ++r) {
            const float* brow = bias + (size_t)(q0 + rowg_l + r) * SEQ + colg;
            bb[r][0] = brow[0]; bb[r][1] = brow[16]; bb[r][2] = brow[32]; bb[r][3] = brow[48];
        }

        // 2. QK^T
        f32x4 acc[4] = {{0,0,0,0},{0,0,0,0},{0,0,0,0},{0,0,0,0}};
        __builtin_amdgcn_s_setprio(1);
        #pragma unroll
        for (int c = 0; c < 4; ++c) {
            bf16x8 bf = *(const bf16x8*)kadr(smem, curK, (ch * 4 + c) * 16 + lm, lq * 16);
            acc[c] = __builtin_amdgcn_mfma_f32_16x16x32_bf16(aQ0, bf, acc[c], 0, 0, 0);
        }
        #pragma unroll
        for (int c = 0; c < 4; ++c) {
            bf16x8 bf = *(const bf16x8*)kadr(smem, curK, (ch * 4 + c) * 16 + lm, 64 + lq * 16);
            acc[c] = __builtin_amdgcn_mfma_f32_16x16x32_bf16(aQ1, bf, acc[c], 0, 0, 0);
        }
        __builtin_amdgcn_s_setprio(0);

        // e = exp(x*scale + bias) -> xs (f32); lane-local sums only
        #pragma unroll
        for (int r = 0; r < 4; ++r) {
            float e0 = __expf(acc[0][r] * scale + bb[r][0]);
            float e1 = __expf(acc[1][r] * scale + bb[r][1]);
            float e2 = __expf(acc[2][r] * scale + bb[r][2]);
            float e3 = __expf(acc[3][r] * scale + bb[r][3]);
            ssum[r] += (e0 + e1) + (e2 + e3);
            xs[kt][0][r] = e0; xs[kt][1][r] = e1; xs[kt][2][r] = e2; xs[kt][3][r] = e3;
        }

        // 3. B1: PV(kt-1) reads of nxt-buffers and sP are done
        __syncthreads();

        // 4. write next K/V tiles -> LDS (vmcnt waits land here, not at a barrier drain)
        if (kt < NKT - 1) {
            #pragma unroll
            for (int i = 0; i < 8; ++i) {
                bf16x4 b;
                b[0] = (__bf16)kv[i][0]; b[1] = (__bf16)kv[i][1];
                b[2] = (__bf16)kv[i][2]; b[3] = (__bf16)kv[i][3];
                *(bf16x4*)kadr(smem, nxtK, srow + 16 * i, sdg * 8) = b;
            }
            #pragma unroll
            for (int i = 0; i < 2; ++i) {
                int d0 = (vdb0 + 8 * i) * 4;
                #pragma unroll
                for (int jj = 0; jj < 4; ++jj) {
                    bf16x4 b;
                    b[0] = (__bf16)vv[i][0][jj]; b[1] = (__bf16)vv[i][1][jj];
                    b[2] = (__bf16)vv[i][2][jj]; b[3] = (__bf16)vv[i][3][jj];
                    *(bf16x4*)vadr(smem, nxtV, d0 + jj, vkb * 8) = b;
                }
            }
        }
        // 5. write sP = raw e (bf16), swizzled -> read side conflict-free
        #pragma unroll
        for (int r = 0; r < 4; ++r) {
            #pragma unroll
            for (int c = 0; c < 4; ++c)
                *(__bf16*)vadr(smem, SPO, rowg_l + r, ch * 128 + 32 * c + 2 * lm) =
                    (__bf16)xs[kt][c][r];
        }
        // 6. B2: sP(kt) + K/V(kt+1) visible
        __syncthreads();

        // 7. PV on unnormalized e
        __builtin_amdgcn_s_setprio(1);
        #pragma unroll
        for (int ks = 0; ks < 4; ++ks) {
            bf16x8 af = *(const bf16x8*)vadr(smem, SPO, qt * 16 + lm, ks * 64 + lq * 16);
            #pragma unroll
            for (int c = 0; c < 2; ++c) {
                bf16x8 bf = *(const bf16x8*)vadr(smem, curV, (dtb + c) * 16 + lm, ks * 64 + lq * 16);
                oacc[c] = __builtin_amdgcn_mfma_f32_16x16x32_bf16(af, bf, oacc[c], 0, 0, 0);
            }
        }
        __builtin_amdgcn_s_setprio(0);
    }

    // ---- row sums: reduce across 16 lm lanes, combine column halves ----
    #pragma unroll
    for (int r = 0; r < 4; ++r) {
        float s = ssum[r];
        #pragma unroll
        for (int off = 1; off < 16; off <<= 1)
            s += __shfl_xor(s, off);
        ssum[r] = s;
    }
    float* sRLp = (float*)(smem + SRL);
    if (lm == 0) {
        #pragma unroll
        for (int r = 0; r < 4; ++r)
            sRLp[ch * 32 + rowg_l + r] = ssum[r];
    }
    __syncthreads();
    float linv[4];
    #pragma unroll
    for (int r = 0; r < 4; ++r)
        linv[r] = 1.0f / (sRLp[rowg_l + r] + sRLp[32 + rowg_l + r]);

    // ---- attn epilogue: barrier-free NT store burst (32 f32x4 per thread) ----
    const bool b0 = (lm & 1) != 0;
    const bool b1 = (lm & 2) != 0;
    const int  rowt = qt * 16 + lq * 4 + j4;   // transposed row this lane stores
    #pragma unroll
    for (int kt = 0; kt < NKT; ++kt) {
        #pragma unroll
        for (int c = 0; c < 4; ++c) {
            float v0 = xs[kt][c][0] * linv[0];
            float v1 = xs[kt][c][1] * linv[1];
            float v2 = xs[kt][c][2] * linv[2];
            float v3 = xs[kt][c][3] * linv[3];
            // 4x4 transpose across lanes j4 (xor 1 then xor 2)
            { float a = b0 ? v0 : v1; float t = __shfl_xor(a, 1); if (b0) v0 = t; else v1 = t; }
            { float a = b0 ? v2 : v3; float t = __shfl_xor(a, 1); if (b0) v2 = t; else v3 = t; }
            { float a = b1 ? v0 : v2; float t = __shfl_xor(a, 2); if (b1) v0 = t; else v2 = t; }
            { float a = b1 ? v1 : v3; float t = __shfl_xor(a, 2); if (b1) v1 = t; else v3 = t; }
            f32x4 wv; wv[0] = v0; wv[1] = v1; wv[2] = v2; wv[3] = v3;
            float* ap = attnh + (size_t)(q0 + rowt) * SEQ + kt * KT + ch * 64 + 16 * c + m0v;
            __builtin_nontemporal_store(wv, (f32x4*)ap);
        }
    }

    // ---- out: scale unnormalized PV accumulator by linv ----
    #pragma unroll
    for (int c = 0; c < 2; ++c)
        #pragma unroll
        for (int r = 0; r < 4; ++r)
            __builtin_nontemporal_store(oacc[c][r] * linv[r],
                outh + (size_t)(q0 + rowg_l + r) * DH + (dtb + c) * 16 + lm);
}

extern "C" void kernel_launch(void* const* d_in, const int* in_sizes, int n_in,
                              void* d_out, int out_size, void* d_ws, size_t ws_size,
                              hipStream_t stream) {
    const float* Q    = (const float*)d_in[0];
    const float* K    = (const float*)d_in[1];
    const float* V    = (const float*)d_in[2];
    const float* bias = (const float*)d_in[3];
    float* out  = (float*)d_out;
    float* attn = (float*)d_out + 4 * 16 * 1024 * 64;
    dim3 grid(64 * (SEQ / QR));
    dim3 block(256);
    attn_flash_kernel<<<grid, block, 0, stream>>>(Q, K, V, bias, out, attn);
}